// Round 1
// baseline (1801.333 us; speedup 1.0000x reference)
//
#include <hip/hip_runtime.h>
#include <cstdint>
#include <cstddef>

// Problem constants
#define B_   8
#define S_   1024
#define D_   1024
#define H_   16
#define HD_  64
#define F_   4096
#define V_   8192
#define KTOP 64

typedef unsigned short ushort_t;
typedef __attribute__((ext_vector_type(8))) short short8;            // MFMA bf16 A/B frag (4 VGPR)
typedef __attribute__((ext_vector_type(4))) float floatx4;           // MFMA C/D frag
typedef __attribute__((ext_vector_type(4))) unsigned int uintx4;     // 16B copy
typedef __attribute__((ext_vector_type(4))) float floatv4;
typedef __attribute__((ext_vector_type(4))) unsigned short ushortx4;
typedef __attribute__((ext_vector_type(8))) unsigned short ushortx8;

__device__ __forceinline__ ushort_t f2bf(float f) {
    unsigned int u = __builtin_bit_cast(unsigned int, f);
    u += 0x7fffu + ((u >> 16) & 1u);            // round-to-nearest-even
    return (ushort_t)(u >> 16);
}
__device__ __forceinline__ float bf2f(ushort_t u) {
    unsigned int x = ((unsigned int)u) << 16;
    return __builtin_bit_cast(float, x);
}

// ---------------------------------------------------------------- cast x -> bf16
__global__ __launch_bounds__(256) void cast_x_kernel(const float* __restrict__ x,
                                                     ushort_t* __restrict__ xb) {
    int gid = blockIdx.x * 256 + threadIdx.x;   // 4 elems per thread
    floatv4 v = ((const floatv4*)x)[gid];
    ushortx4 o;
    o[0] = f2bf(v[0]); o[1] = f2bf(v[1]); o[2] = f2bf(v[2]); o[3] = f2bf(v[3]);
    ((ushortx4*)xb)[gid] = o;
}

// ------------------------------------------- transpose + cast weight: W(K,N) -> WT(N,K) bf16
__global__ void transpose_cast_kernel(const float* __restrict__ W, ushort_t* __restrict__ WT,
                                      int K, int N) {
    __shared__ float tile[32][33];
    int n0 = blockIdx.x * 32, k0 = blockIdx.y * 32;
    #pragma unroll
    for (int i = threadIdx.y; i < 32; i += 8)
        tile[i][threadIdx.x] = W[(size_t)(k0 + i) * N + n0 + threadIdx.x];
    __syncthreads();
    #pragma unroll
    for (int i = threadIdx.y; i < 32; i += 8)
        WT[(size_t)(n0 + i) * K + k0 + threadIdx.x] = f2bf(tile[threadIdx.x][i]);
}

// ---------------------------------------------------------------- pmi bias gather (ALPHA folded)
__global__ __launch_bounds__(256) void bias_gather_kernel(const int* __restrict__ tok,
                                                          const float* __restrict__ pmi,
                                                          ushort_t* __restrict__ biasb) {
    int b = blockIdx.x >> 10;
    int i = blockIdx.x & (S_ - 1);
    int ti = tok[b * S_ + i];
    const float* prow = pmi + (size_t)ti * V_;
    #pragma unroll
    for (int it = 0; it < 4; it++) {
        int j = threadIdx.x + it * 256;
        int tj = tok[b * S_ + j];
        biasb[(size_t)blockIdx.x * S_ + j] = f2bf(0.1f * prow[tj]);
    }
}

// ---------------------------------------------------------------- V (B,H,S,HD) -> vT (B,H,HD,S)
__global__ __launch_bounds__(256) void transpose_v_kernel(const ushort_t* __restrict__ v,
                                                          ushort_t* __restrict__ vT) {
    __shared__ ushort_t t[64 * 72];   // [s_loc][d], stride 72
    int bh = blockIdx.x >> 4;
    int s0 = (blockIdx.x & 15) * 64;
    #pragma unroll
    for (int it = 0; it < 2; it++) {
        int idx = threadIdx.x + it * 256;
        int sl = idx >> 3, dg = (idx & 7) * 8;
        *(uintx4*)&t[sl * 72 + dg] = *(const uintx4*)&v[((size_t)bh * S_ + s0 + sl) * HD_ + dg];
    }
    __syncthreads();
    #pragma unroll
    for (int it = 0; it < 2; it++) {
        int idx = threadIdx.x + it * 256;
        int dl = idx >> 3, sg = (idx & 7) * 8;
        ushortx8 o;
        #pragma unroll
        for (int i = 0; i < 8; i++) o[i] = t[(sg + i) * 72 + dl];
        *(ushortx8*)&vT[((size_t)bh * HD_ + dl) * S_ + s0 + sg] = o;
    }
}

// ---------------------------------------------------------------- GEMM: C = A(M,K) @ BT(N,K)^T + bias
// ep: 0 = bf16 row-major out ; 1 = + exact GELU ; 2 = QKV head layout (B,H,S,HD)
__global__ __launch_bounds__(256) void gemm_bt(const ushort_t* __restrict__ A,
                                               const ushort_t* __restrict__ BT,
                                               const float* __restrict__ bias,
                                               ushort_t* __restrict__ C,
                                               int M, int N, int K, int ep) {
    extern __shared__ char smem[];
    ushort_t* As = (ushort_t*)smem;            // 128 x 40 (pad +8 -> 2-way bank = free)
    ushort_t* Bs = As + 128 * 40;              // 128 x 40

    const int tid = threadIdx.x;
    const int wid = tid >> 6, lane = tid & 63;
    const int quad = lane >> 4, r = lane & 15;
    const int wr = wid >> 1, wc = wid & 1;
    const int m0 = blockIdx.y * 128, n0 = blockIdx.x * 128;

    floatx4 acc[4][4];
    #pragma unroll
    for (int a = 0; a < 4; a++)
        #pragma unroll
        for (int b = 0; b < 4; b++) acc[a][b] = (floatx4){0.f, 0.f, 0.f, 0.f};

    const int row1 = tid >> 2, o1 = (tid & 3) * 8;   // 16B segment per thread, x2 rows
    const int row2 = row1 + 64;

    for (int k0 = 0; k0 < K; k0 += 32) {
        __syncthreads();
        *(uintx4*)&As[row1 * 40 + o1] = *(const uintx4*)&A[(size_t)(m0 + row1) * K + k0 + o1];
        *(uintx4*)&As[row2 * 40 + o1] = *(const uintx4*)&A[(size_t)(m0 + row2) * K + k0 + o1];
        *(uintx4*)&Bs[row1 * 40 + o1] = *(const uintx4*)&BT[(size_t)(n0 + row1) * K + k0 + o1];
        *(uintx4*)&Bs[row2 * 40 + o1] = *(const uintx4*)&BT[(size_t)(n0 + row2) * K + k0 + o1];
        __syncthreads();

        short8 af[4], bf[4];
        #pragma unroll
        for (int t = 0; t < 4; t++)
            af[t] = *(const short8*)&As[(wr * 64 + t * 16 + r) * 40 + quad * 8];
        #pragma unroll
        for (int t = 0; t < 4; t++)
            bf[t] = *(const short8*)&Bs[(wc * 64 + t * 16 + r) * 40 + quad * 8];
        #pragma unroll
        for (int tm = 0; tm < 4; tm++)
            #pragma unroll
            for (int tn = 0; tn < 4; tn++)
                acc[tm][tn] = __builtin_amdgcn_mfma_f32_16x16x32_bf16(af[tm], bf[tn], acc[tm][tn], 0, 0, 0);
    }

    #pragma unroll
    for (int tm = 0; tm < 4; tm++) {
        #pragma unroll
        for (int tn = 0; tn < 4; tn++) {
            const int n = n0 + wc * 64 + tn * 16 + r;      // C col = lane&15 (m89-verified)
            const float bv = bias[n];
            #pragma unroll
            for (int i2 = 0; i2 < 4; i2++) {
                const int m = m0 + wr * 64 + tm * 16 + quad * 4 + i2;  // row = quad*4+reg
                float v = acc[tm][tn][i2] + bv;
                if (ep == 1) v = 0.5f * v * (1.0f + erff(v * 0.70710678118654752f));
                size_t idx;
                if (ep == 2) {
                    // (b,s) x (h,d) -> (B,H,S,HD)
                    idx = ((size_t)((m >> 10) * H_ + (n >> 6)) * S_ + (m & (S_ - 1))) * HD_ + (n & (HD_ - 1));
                } else {
                    idx = (size_t)m * N + n;
                }
                C[idx] = f2bf(v);
            }
        }
    }
}

// ---------------------------------------------------------------- fused attention (per b,h,16-query tile)
__global__ __launch_bounds__(256) void attn_kernel(const ushort_t* __restrict__ q,
                                                   const ushort_t* __restrict__ k,
                                                   const ushort_t* __restrict__ vT,
                                                   const ushort_t* __restrict__ biasb,
                                                   ushort_t* __restrict__ attnb) {
    extern __shared__ char smem[];
    ushort_t* q_lds = (ushort_t*)smem;            // 16 x 72 bf16
    float* Sm = (float*)(smem + 2304);            // 16 x 1028 fp32 (stride 4112B, 16B aligned)
    const int SST = 1028;

    const int bid = blockIdx.x;
    const int b = bid >> 10;
    const int h = (bid >> 6) & (H_ - 1);
    const int i0 = (bid & 63) * 16;
    const int tid = threadIdx.x;
    const int wid = tid >> 6, lane = tid & 63;
    const int quad = lane >> 4, r = lane & 15;

    const size_t bh = (size_t)b * H_ + h;
    const ushort_t* qbase = q + bh * S_ * HD_;
    const ushort_t* kbase = k + bh * S_ * HD_;
    const ushort_t* vbase = vT + bh * HD_ * S_;
    const ushort_t* bbase = biasb + ((size_t)b * S_ + i0) * S_;

    if (tid < 128) {
        int row = tid >> 3, dg = (tid & 7) * 8;
        *(uintx4*)&q_lds[row * 72 + dg] = *(const uintx4*)&qbase[(size_t)(i0 + row) * HD_ + dg];
    }
    __syncthreads();

    // ---- QK^T: scores into LDS (scaled + pmi bias)
    short8 aq0 = *(const short8*)&q_lds[r * 72 + quad * 8];        // A[m=lane&15][k=quad*8+j]
    short8 aq1 = *(const short8*)&q_lds[r * 72 + 32 + quad * 8];
    for (int t = 0; t < 16; t++) {
        int jt = (t * 4 + wid) * 16;
        floatx4 acc = (floatx4){0.f, 0.f, 0.f, 0.f};
        const ushort_t* kp = kbase + (size_t)(jt + r) * HD_ + quad * 8;  // B[k][n=lane&15] = K[n][k]
        short8 b0 = *(const short8*)kp;
        short8 b1 = *(const short8*)(kp + 32);
        acc = __builtin_amdgcn_mfma_f32_16x16x32_bf16(aq0, b0, acc, 0, 0, 0);
        acc = __builtin_amdgcn_mfma_f32_16x16x32_bf16(aq1, b1, acc, 0, 0, 0);
        #pragma unroll
        for (int i2 = 0; i2 < 4; i2++) {
            int row = quad * 4 + i2;
            float bvv = bf2f(bbase[(size_t)row * S_ + jt + r]);
            Sm[row * SST + jt + r] = acc[i2] * 0.125f + bvv;   // 1/sqrt(64), ALPHA pre-folded
        }
    }
    __syncthreads();

    // ---- exact top-64 (bitwise radix select on order-mapped keys) + softmax, 4 rows/wave.
    // Weights written bf16 in-place over the score row (all reads complete before writes).
    for (int rr = 0; rr < 4; rr++) {
        int row = wid * 4 + rr;
        float* Srow = Sm + row * SST;
        float sv[16]; unsigned int kk[16];
        float mx = -3.4e38f;
        #pragma unroll
        for (int t = 0; t < 16; t++) {
            sv[t] = Srow[t * 64 + lane];
            unsigned int u = __builtin_bit_cast(unsigned int, sv[t]);
            kk[t] = (u & 0x80000000u) ? ~u : (u | 0x80000000u);
            mx = fmaxf(mx, sv[t]);
        }
        #pragma unroll
        for (int off = 32; off; off >>= 1) mx = fmaxf(mx, __shfl_xor(mx, off));
        unsigned int T = 0u;                       // largest T with count(key>=T) >= 64  == kth largest
        for (int bit = 31; bit >= 0; bit--) {
            unsigned int trial = T | (1u << bit);
            int c = 0;
            #pragma unroll
            for (int t = 0; t < 16; t++) c += (kk[t] >= trial) ? 1 : 0;
            #pragma unroll
            for (int off = 32; off; off >>= 1) c += __shfl_xor(c, off);
            if (c >= KTOP) T = trial;
        }
        float ev[16]; float sum = 0.f;
        #pragma unroll
        for (int t = 0; t < 16; t++) {
            ev[t] = (kk[t] >= T) ? __expf(sv[t] - mx) : 0.f;   // keep iff score >= kth (ties kept)
            sum += ev[t];
        }
        #pragma unroll
        for (int off = 32; off; off >>= 1) sum += __shfl_xor(sum, off);
        float inv = 1.f / sum;
        ushort_t* wrow = (ushort_t*)Srow;
        #pragma unroll
        for (int t = 0; t < 16; t++) wrow[t * 64 + lane] = f2bf(ev[t] * inv);
    }
    __syncthreads();

    // ---- PV: attn(16 x 64) = W(16 x 1024) @ V(1024 x 64); wave wid owns d-tile wid*16
    floatx4 oacc = (floatx4){0.f, 0.f, 0.f, 0.f};
    const int SSTB = SST * 4;   // 4112 bytes per (w) row
    for (int ks = 0; ks < 32; ks++) {
        short8 wa = *(const short8*)((const char*)Sm + (size_t)r * SSTB + ks * 64 + quad * 16);
        short8 vbf = *(const short8*)&vbase[(size_t)(wid * 16 + r) * S_ + ks * 32 + quad * 8];
        oacc = __builtin_amdgcn_mfma_f32_16x16x32_bf16(wa, vbf, oacc, 0, 0, 0);
    }
    #pragma unroll
    for (int i2 = 0; i2 < 4; i2++) {
        int row = quad * 4 + i2;
        attnb[((size_t)b * S_ + i0 + row) * D_ + h * HD_ + wid * 16 + r] = f2bf(oacc[i2]);
    }
}

// ---------------------------------------------------------------- layernorm kernels
__global__ __launch_bounds__(256) void ln1_kernel(const float* __restrict__ x,
                                                  const ushort_t* __restrict__ t,
                                                  const float* __restrict__ g,
                                                  const float* __restrict__ be,
                                                  ushort_t* __restrict__ hb) {
    int row = blockIdx.x, tid = threadIdx.x;
    const float* xr = x + (size_t)row * D_;
    const ushort_t* tr = t + (size_t)row * D_;
    float v[4]; float s = 0.f, s2 = 0.f;
    #pragma unroll
    for (int it = 0; it < 4; it++) {
        int j = tid + it * 256;
        v[it] = xr[j] + bf2f(tr[j]);
        s += v[it]; s2 += v[it] * v[it];
    }
    #pragma unroll
    for (int off = 32; off; off >>= 1) { s += __shfl_xor(s, off); s2 += __shfl_xor(s2, off); }
    __shared__ float rs[4], rq[4];
    if ((tid & 63) == 0) { rs[tid >> 6] = s; rq[tid >> 6] = s2; }
    __syncthreads();
    s = rs[0] + rs[1] + rs[2] + rs[3];
    s2 = rq[0] + rq[1] + rq[2] + rq[3];
    float mu = s * (1.f / D_);
    float var = s2 * (1.f / D_) - mu * mu;
    float rstd = rsqrtf(var + 1e-5f);
    #pragma unroll
    for (int it = 0; it < 4; it++) {
        int j = tid + it * 256;
        hb[(size_t)row * D_ + j] = f2bf((v[it] - mu) * rstd * g[j] + be[j]);
    }
}

__global__ __launch_bounds__(256) void ln2_kernel(const ushort_t* __restrict__ hbuf,
                                                  const ushort_t* __restrict__ t,
                                                  const float* __restrict__ g,
                                                  const float* __restrict__ be,
                                                  float* __restrict__ out) {
    int row = blockIdx.x, tid = threadIdx.x;
    const ushort_t* hr = hbuf + (size_t)row * D_;
    const ushort_t* tr = t + (size_t)row * D_;
    float v[4]; float s = 0.f, s2 = 0.f;
    #pragma unroll
    for (int it = 0; it < 4; it++) {
        int j = tid + it * 256;
        v[it] = bf2f(hr[j]) + bf2f(tr[j]);
        s += v[it]; s2 += v[it] * v[it];
    }
    #pragma unroll
    for (int off = 32; off; off >>= 1) { s += __shfl_xor(s, off); s2 += __shfl_xor(s2, off); }
    __shared__ float rs[4], rq[4];
    if ((tid & 63) == 0) { rs[tid >> 6] = s; rq[tid >> 6] = s2; }
    __syncthreads();
    s = rs[0] + rs[1] + rs[2] + rs[3];
    s2 = rq[0] + rq[1] + rq[2] + rq[3];
    float mu = s * (1.f / D_);
    float var = s2 * (1.f / D_) - mu * mu;
    float rstd = rsqrtf(var + 1e-5f);
    #pragma unroll
    for (int it = 0; it < 4; it++) {
        int j = tid + it * 256;
        out[(size_t)row * D_ + j] = (v[it] - mu) * rstd * g[j] + be[j];
    }
}

// ---------------------------------------------------------------- launch
extern "C" void kernel_launch(void* const* d_in, const int* in_sizes, int n_in,
                              void* d_out, int out_size, void* d_ws, size_t ws_size,
                              hipStream_t stream) {
    (void)in_sizes; (void)n_in; (void)out_size; (void)ws_size;
    const float* x   = (const float*)d_in[0];
    const int*   tok = (const int*)d_in[1];
    const float* pmi = (const float*)d_in[2];
    const float* Wq  = (const float*)d_in[3];
    const float* bq  = (const float*)d_in[4];
    const float* Wk  = (const float*)d_in[5];
    const float* bk  = (const float*)d_in[6];
    const float* Wv  = (const float*)d_in[7];
    const float* bv  = (const float*)d_in[8];
    const float* Wo  = (const float*)d_in[9];
    const float* bo  = (const float*)d_in[10];
    const float* W1  = (const float*)d_in[11];
    const float* b1  = (const float*)d_in[12];
    const float* W2  = (const float*)d_in[13];
    const float* b2  = (const float*)d_in[14];
    const float* g1  = (const float*)d_in[15];
    const float* be1 = (const float*)d_in[16];
    const float* g2  = (const float*)d_in[17];
    const float* be2 = (const float*)d_in[18];
    float* out = (float*)d_out;

    char* ws = (char*)d_ws;
    size_t off = 0;
    auto alloc = [&](size_t bytes) { char* p = ws + off; off += (bytes + 255) & ~(size_t)255; return p; };
    ushort_t* xb    = (ushort_t*)alloc((size_t)B_ * S_ * D_ * 2);      // 16.8 MB
    ushort_t* WqT   = (ushort_t*)alloc((size_t)D_ * D_ * 2);
    ushort_t* WkT   = (ushort_t*)alloc((size_t)D_ * D_ * 2);
    ushort_t* WvT   = (ushort_t*)alloc((size_t)D_ * D_ * 2);
    ushort_t* WoT   = (ushort_t*)alloc((size_t)D_ * D_ * 2);
    ushort_t* W1T   = (ushort_t*)alloc((size_t)D_ * F_ * 2);
    ushort_t* W2T   = (ushort_t*)alloc((size_t)F_ * D_ * 2);
    ushort_t* qb    = (ushort_t*)alloc((size_t)B_ * S_ * D_ * 2);
    ushort_t* kb    = (ushort_t*)alloc((size_t)B_ * S_ * D_ * 2);
    ushort_t* vb    = (ushort_t*)alloc((size_t)B_ * S_ * D_ * 2);
    ushort_t* vT    = (ushort_t*)alloc((size_t)B_ * S_ * D_ * 2);
    ushort_t* biasb = (ushort_t*)alloc((size_t)B_ * S_ * S_ * 2);
    ushort_t* extra = (ushort_t*)alloc((size_t)B_ * S_ * D_ * 2);
    (void)extra;
    // aliases (strict stream-order reuse; no overlap of live ranges)
    ushort_t* attnb = xb;    // xb dead after QKV GEMMs
    ushort_t* tbuf  = qb;    // q dead after attention
    ushort_t* hb    = kb;    // k dead after attention
    ushort_t* ffb   = vb;    // v,vT,biasb,extra contiguous (67.1 MB) dead after attention

    const size_t gemm_lds = 2 * 128 * 40 * sizeof(ushort_t);   // 20480 B
    const size_t attn_lds = 2304 + 16 * 1028 * 4;              // 68096 B

    cast_x_kernel<<<8192, 256, 0, stream>>>(x, xb);
    transpose_cast_kernel<<<dim3(32, 32), dim3(32, 8), 0, stream>>>(Wq, WqT, D_, D_);
    transpose_cast_kernel<<<dim3(32, 32), dim3(32, 8), 0, stream>>>(Wk, WkT, D_, D_);
    transpose_cast_kernel<<<dim3(32, 32), dim3(32, 8), 0, stream>>>(Wv, WvT, D_, D_);
    transpose_cast_kernel<<<dim3(32, 32), dim3(32, 8), 0, stream>>>(Wo, WoT, D_, D_);
    transpose_cast_kernel<<<dim3(128, 32), dim3(32, 8), 0, stream>>>(W1, W1T, D_, F_);
    transpose_cast_kernel<<<dim3(32, 128), dim3(32, 8), 0, stream>>>(W2, W2T, F_, D_);
    bias_gather_kernel<<<B_ * S_, 256, 0, stream>>>(tok, pmi, biasb);

    gemm_bt<<<dim3(8, 64), 256, gemm_lds, stream>>>(xb, WqT, bq, qb, B_ * S_, D_, D_, 2);
    gemm_bt<<<dim3(8, 64), 256, gemm_lds, stream>>>(xb, WkT, bk, kb, B_ * S_, D_, D_, 2);
    gemm_bt<<<dim3(8, 64), 256, gemm_lds, stream>>>(xb, WvT, bv, vb, B_ * S_, D_, D_, 2);
    transpose_v_kernel<<<B_ * H_ * (S_ / 64), 256, 0, stream>>>(vb, vT);

    attn_kernel<<<B_ * H_ * (S_ / 16), 256, attn_lds, stream>>>(qb, kb, vT, biasb, attnb);

    gemm_bt<<<dim3(8, 64), 256, gemm_lds, stream>>>(attnb, WoT, bo, tbuf, B_ * S_, D_, D_, 0);
    ln1_kernel<<<B_ * S_, 256, 0, stream>>>(x, tbuf, g1, be1, hb);
    gemm_bt<<<dim3(32, 64), 256, gemm_lds, stream>>>(hb, W1T, b1, ffb, B_ * S_, F_, D_, 1);
    gemm_bt<<<dim3(8, 64), 256, gemm_lds, stream>>>(ffb, W2T, b2, tbuf, B_ * S_, D_, F_, 0);
    ln2_kernel<<<B_ * S_, 256, 0, stream>>>(hb, tbuf, g2, be2, out);
}

// Round 2
// 1425.570 us; speedup vs baseline: 1.2636x; 1.2636x over previous
//
#include <hip/hip_runtime.h>
#include <cstdint>
#include <cstddef>

// Problem constants
#define B_   8
#define S_   1024
#define D_   1024
#define H_   16
#define HD_  64
#define F_   4096
#define V_   8192
#define KTOP 64

typedef unsigned short ushort_t;
typedef __attribute__((ext_vector_type(8))) short short8;            // MFMA bf16 A/B frag (4 VGPR)
typedef __attribute__((ext_vector_type(4))) float floatx4;           // MFMA C/D frag
typedef __attribute__((ext_vector_type(4))) unsigned int uintx4;     // 16B copy
typedef __attribute__((ext_vector_type(4))) float floatv4;
typedef __attribute__((ext_vector_type(4))) unsigned short ushortx4;
typedef __attribute__((ext_vector_type(8))) unsigned short ushortx8;

__device__ __forceinline__ ushort_t f2bf(float f) {
    unsigned int u = __builtin_bit_cast(unsigned int, f);
    u += 0x7fffu + ((u >> 16) & 1u);            // round-to-nearest-even
    return (ushort_t)(u >> 16);
}
__device__ __forceinline__ float bf2f(ushort_t u) {
    unsigned int x = ((unsigned int)u) << 16;
    return __builtin_bit_cast(float, x);
}

// async global->LDS, 16B per lane; lds dest = wave-uniform base + lane*16
__device__ __forceinline__ void gload_lds16(const ushort_t* g, ushort_t* lds_base) {
    __builtin_amdgcn_global_load_lds(
        (const __attribute__((address_space(1))) unsigned int*)g,
        (__attribute__((address_space(3))) unsigned int*)lds_base,
        16, 0, 0);
}

// ---------------------------------------------------------------- cast x -> bf16
__global__ __launch_bounds__(256) void cast_x_kernel(const float* __restrict__ x,
                                                     ushort_t* __restrict__ xb) {
    int gid = blockIdx.x * 256 + threadIdx.x;   // 4 elems per thread
    floatv4 v = ((const floatv4*)x)[gid];
    ushortx4 o;
    o[0] = f2bf(v[0]); o[1] = f2bf(v[1]); o[2] = f2bf(v[2]); o[3] = f2bf(v[3]);
    ((ushortx4*)xb)[gid] = o;
}

// ------------------------------------------- transpose + cast weight: W(K,N) -> WT(N,K) bf16
__global__ void transpose_cast_kernel(const float* __restrict__ W, ushort_t* __restrict__ WT,
                                      int K, int N) {
    __shared__ float tile[32][33];
    int n0 = blockIdx.x * 32, k0 = blockIdx.y * 32;
    #pragma unroll
    for (int i = threadIdx.y; i < 32; i += 8)
        tile[i][threadIdx.x] = W[(size_t)(k0 + i) * N + n0 + threadIdx.x];
    __syncthreads();
    #pragma unroll
    for (int i = threadIdx.y; i < 32; i += 8)
        WT[(size_t)(n0 + i) * K + k0 + threadIdx.x] = f2bf(tile[threadIdx.x][i]);
}

// ---------------------------------------------------------------- pack q/k/v biases
__global__ __launch_bounds__(256) void pack_bias3_kernel(const float* __restrict__ bq,
                                                         const float* __restrict__ bk,
                                                         const float* __restrict__ bv,
                                                         float* __restrict__ o) {
    int i = blockIdx.x * 256 + threadIdx.x;   // 3072 total
    float v = (i < 1024) ? bq[i] : (i < 2048) ? bk[i - 1024] : bv[i - 2048];
    o[i] = v;
}

// ---------------------------------------------------------------- pmi bias gather (ALPHA folded)
__global__ __launch_bounds__(256) void bias_gather_kernel(const int* __restrict__ tok,
                                                          const float* __restrict__ pmi,
                                                          ushort_t* __restrict__ biasb) {
    int b = blockIdx.x >> 10;
    int i = blockIdx.x & (S_ - 1);
    int ti = tok[b * S_ + i];
    const float* prow = pmi + (size_t)ti * V_;
    #pragma unroll
    for (int it = 0; it < 4; it++) {
        int j = threadIdx.x + it * 256;
        int tj = tok[b * S_ + j];
        biasb[(size_t)blockIdx.x * S_ + j] = f2bf(0.1f * prow[tj]);
    }
}

// ---------------------------------------------------------------- V (B,H,S,HD) -> vT (B,H,HD,S)
__global__ __launch_bounds__(256) void transpose_v_kernel(const ushort_t* __restrict__ v,
                                                          ushort_t* __restrict__ vT) {
    __shared__ ushort_t t[64 * 72];   // [s_loc][d], stride 72
    int bh = blockIdx.x >> 4;
    int s0 = (blockIdx.x & 15) * 64;
    #pragma unroll
    for (int it = 0; it < 2; it++) {
        int idx = threadIdx.x + it * 256;
        int sl = idx >> 3, dg = (idx & 7) * 8;
        *(uintx4*)&t[sl * 72 + dg] = *(const uintx4*)&v[((size_t)bh * S_ + s0 + sl) * HD_ + dg];
    }
    __syncthreads();
    #pragma unroll
    for (int it = 0; it < 2; it++) {
        int idx = threadIdx.x + it * 256;
        int dl = idx >> 3, sg = (idx & 7) * 8;
        ushortx8 o;
        #pragma unroll
        for (int i = 0; i < 8; i++) o[i] = t[(sg + i) * 72 + dl];
        *(ushortx8*)&vT[((size_t)bh * HD_ + dl) * S_ + s0 + sg] = o;
    }
}

// ---------------------------------------------------------------- GEMM: C = A(M,K) @ BT(N,K)^T + bias
// ep: 0 = bf16 row-major out ; 1 = + exact GELU ; 2 = fused QKV -> (3,B,H,S,HD)
__global__ __launch_bounds__(256) void gemm_bt(const ushort_t* __restrict__ A,
                                               const ushort_t* __restrict__ BT,
                                               const float* __restrict__ bias,
                                               ushort_t* __restrict__ C,
                                               int M, int N, int K, int ep) {
    __shared__ ushort_t As[128 * 32];   // unpadded: required by global_load_lds lane mapping
    __shared__ ushort_t Bs[128 * 32];

    const int tid = threadIdx.x;
    const int wid = tid >> 6, lane = tid & 63;
    const int quad = lane >> 4, r = lane & 15;
    const int wr = wid >> 1, wc = wid & 1;
    const int m0 = blockIdx.y * 128, n0 = blockIdx.x * 128;

    floatx4 acc[4][4];
    #pragma unroll
    for (int a = 0; a < 4; a++)
        #pragma unroll
        for (int b = 0; b < 4; b++) acc[a][b] = (floatx4){0.f, 0.f, 0.f, 0.f};

    // staging map: wave wid covers 16 rows/call; lane -> (row=lane>>2, col8=(lane&3)*8)
    const int srow = wid * 16 + (lane >> 2);
    const int scol = (lane & 3) * 8;
    const ushort_t* Ag0 = A + (size_t)(m0 + srow) * K + scol;
    const ushort_t* Ag1 = A + (size_t)(m0 + 64 + srow) * K + scol;
    const ushort_t* Bg0 = BT + (size_t)(n0 + srow) * K + scol;
    const ushort_t* Bg1 = BT + (size_t)(n0 + 64 + srow) * K + scol;
    ushort_t* Asd0 = As + (wid * 16) * 32;
    ushort_t* Asd1 = As + (64 + wid * 16) * 32;
    ushort_t* Bsd0 = Bs + (wid * 16) * 32;
    ushort_t* Bsd1 = Bs + (64 + wid * 16) * 32;

    for (int k0 = 0; k0 < K; k0 += 32) {
        __syncthreads();
        gload_lds16(Ag0 + k0, Asd0);
        gload_lds16(Ag1 + k0, Asd1);
        gload_lds16(Bg0 + k0, Bsd0);
        gload_lds16(Bg1 + k0, Bsd1);
        __syncthreads();

        short8 af[4], bf[4];
        #pragma unroll
        for (int t = 0; t < 4; t++)
            af[t] = *(const short8*)&As[(wr * 64 + t * 16 + r) * 32 + quad * 8];
        #pragma unroll
        for (int t = 0; t < 4; t++)
            bf[t] = *(const short8*)&Bs[(wc * 64 + t * 16 + r) * 32 + quad * 8];
        #pragma unroll
        for (int tm = 0; tm < 4; tm++)
            #pragma unroll
            for (int tn = 0; tn < 4; tn++)
                acc[tm][tn] = __builtin_amdgcn_mfma_f32_16x16x32_bf16(af[tm], bf[tn], acc[tm][tn], 0, 0, 0);
    }

    #pragma unroll
    for (int tm = 0; tm < 4; tm++) {
        #pragma unroll
        for (int tn = 0; tn < 4; tn++) {
            const int n = n0 + wc * 64 + tn * 16 + r;      // C col = lane&15 (m89-verified)
            const float bv = bias[n];
            #pragma unroll
            for (int i2 = 0; i2 < 4; i2++) {
                const int m = m0 + wr * 64 + tm * 16 + quad * 4 + i2;  // row = quad*4+reg
                float v = acc[tm][tn][i2] + bv;
                if (ep == 1) v = 0.5f * v * (1.0f + erff(v * 0.70710678118654752f));
                size_t idx;
                if (ep == 2) {
                    // (b,s) x (tensor,h,d) -> tensor*(B,H,S,HD)
                    int tensor = n >> 10, nn = n & 1023;
                    idx = (size_t)tensor * (B_ * S_ * D_)
                        + (((size_t)(m >> 10) * H_ + (nn >> 6)) * S_ + (m & (S_ - 1))) * HD_ + (nn & (HD_ - 1));
                } else {
                    idx = (size_t)m * N + n;
                }
                C[idx] = f2bf(v);
            }
        }
    }
}

// ---------------------------------------------------------------- fused attention (per b,h,16-query tile)
__global__ __launch_bounds__(256) void attn_kernel(const ushort_t* __restrict__ q,
                                                   const ushort_t* __restrict__ k,
                                                   const ushort_t* __restrict__ vT,
                                                   const ushort_t* __restrict__ biasb,
                                                   ushort_t* __restrict__ attnb) {
    extern __shared__ char smem[];
    ushort_t* q_lds = (ushort_t*)smem;            // 16 x 72 bf16
    float* Sm = (float*)(smem + 2304);            // 16 x 1028 fp32 (stride 4112B, 16B aligned)
    const int SST = 1028;

    const int bid = blockIdx.x;
    const int b = bid >> 10;
    const int h = (bid >> 6) & (H_ - 1);
    const int i0 = (bid & 63) * 16;
    const int tid = threadIdx.x;
    const int wid = tid >> 6, lane = tid & 63;
    const int quad = lane >> 4, r = lane & 15;

    const size_t bh = (size_t)b * H_ + h;
    const ushort_t* qbase = q + bh * S_ * HD_;
    const ushort_t* kbase = k + bh * S_ * HD_;
    const ushort_t* vbase = vT + bh * HD_ * S_;
    const ushort_t* bbase = biasb + ((size_t)b * S_ + i0) * S_;

    // stage q tile (threads 0..127) and bias rows -> Sm fp32 (all threads, coalesced)
    if (tid < 128) {
        int row = tid >> 3, dg = (tid & 7) * 8;
        *(uintx4*)&q_lds[row * 72 + dg] = *(const uintx4*)&qbase[(size_t)(i0 + row) * HD_ + dg];
    }
    #pragma unroll
    for (int it = 0; it < 8; it++) {
        int idx = tid + it * 256;          // 2048 x 8 elems = 16 x 1024
        int row = idx >> 7, seg = idx & 127;
        ushortx8 bv8 = *(const ushortx8*)&bbase[(size_t)row * S_ + seg * 8];
        float* dst = &Sm[row * SST + seg * 8];
        #pragma unroll
        for (int i = 0; i < 8; i++) dst[i] = bf2f(bv8[i]);
    }
    __syncthreads();

    // ---- QK^T: scores += into LDS (bias pre-staged; 1/sqrt(64) folded)
    short8 aq0 = *(const short8*)&q_lds[r * 72 + quad * 8];        // A[m=lane&15][k=quad*8+j]
    short8 aq1 = *(const short8*)&q_lds[r * 72 + 32 + quad * 8];
    #pragma unroll 4
    for (int t = 0; t < 16; t++) {
        int jt = (t * 4 + wid) * 16;
        floatx4 acc = (floatx4){0.f, 0.f, 0.f, 0.f};
        const ushort_t* kp = kbase + (size_t)(jt + r) * HD_ + quad * 8;  // B[k][n=lane&15] = K[n][k]
        short8 b0 = *(const short8*)kp;
        short8 b1 = *(const short8*)(kp + 32);
        acc = __builtin_amdgcn_mfma_f32_16x16x32_bf16(aq0, b0, acc, 0, 0, 0);
        acc = __builtin_amdgcn_mfma_f32_16x16x32_bf16(aq1, b1, acc, 0, 0, 0);
        #pragma unroll
        for (int i2 = 0; i2 < 4; i2++) {
            int row = quad * 4 + i2;
            float* p = &Sm[row * SST + jt + r];
            *p = *p + acc[i2] * 0.125f;
        }
    }
    __syncthreads();

    // ---- exact-ish top-64: 20-bit radix select, ballot-counted (scalar-pipe counts).
    // Ties at 2^-11-relative granularity are kept (matches `>= kth` semantics within bf16 noise).
    for (int rr = 0; rr < 4; rr++) {
        int row = wid * 4 + rr;
        float* Srow = Sm + row * SST;
        float sv[16]; unsigned int kk[16];
        float mx = -3.4e38f;
        #pragma unroll
        for (int t = 0; t < 16; t++) {
            sv[t] = Srow[t * 64 + lane];
            unsigned int u = __builtin_bit_cast(unsigned int, sv[t]);
            u = (u & 0x80000000u) ? ~u : (u | 0x80000000u);   // order-map
            kk[t] = u >> 12;                                   // 20-bit key
            mx = fmaxf(mx, sv[t]);
        }
        #pragma unroll
        for (int off = 32; off; off >>= 1) mx = fmaxf(mx, __shfl_xor(mx, off));
        unsigned int T = 0u;                 // largest 20-bit T with count(key>=T) >= 64
        for (int bit = 19; bit >= 0; bit--) {
            unsigned int trial = T | (1u << bit);
            int c = 0;
            #pragma unroll
            for (int t = 0; t < 16; t++)
                c += __popcll(__ballot(kk[t] >= trial));
            if (c >= KTOP) T = trial;
        }
        float ev[16]; float sum = 0.f;
        #pragma unroll
        for (int t = 0; t < 16; t++) {
            ev[t] = (kk[t] >= T) ? __expf(sv[t] - mx) : 0.f;
            sum += ev[t];
        }
        #pragma unroll
        for (int off = 32; off; off >>= 1) sum += __shfl_xor(sum, off);
        float inv = 1.f / sum;
        ushort_t* wrow = (ushort_t*)Srow;
        #pragma unroll
        for (int t = 0; t < 16; t++) wrow[t * 64 + lane] = f2bf(ev[t] * inv);
    }
    __syncthreads();

    // ---- PV: attn(16 x 64) = W(16 x 1024) @ V(1024 x 64); wave wid owns d-tile wid*16
    floatx4 oacc = (floatx4){0.f, 0.f, 0.f, 0.f};
    const int SSTB = SST * 4;   // 4112 bytes per weight row
    for (int ks = 0; ks < 32; ks++) {
        short8 wa = *(const short8*)((const char*)Sm + (size_t)r * SSTB + ks * 64 + quad * 16);
        short8 vbf = *(const short8*)&vbase[(size_t)(wid * 16 + r) * S_ + ks * 32 + quad * 8];
        oacc = __builtin_amdgcn_mfma_f32_16x16x32_bf16(wa, vbf, oacc, 0, 0, 0);
    }
    #pragma unroll
    for (int i2 = 0; i2 < 4; i2++) {
        int row = quad * 4 + i2;
        attnb[((size_t)b * S_ + i0 + row) * D_ + h * HD_ + wid * 16 + r] = f2bf(oacc[i2]);
    }
}

// ---------------------------------------------------------------- layernorm kernels
__global__ __launch_bounds__(256) void ln1_kernel(const float* __restrict__ x,
                                                  const ushort_t* __restrict__ t,
                                                  const float* __restrict__ g,
                                                  const float* __restrict__ be,
                                                  ushort_t* __restrict__ hb) {
    int row = blockIdx.x, tid = threadIdx.x;
    const float* xr = x + (size_t)row * D_;
    const ushort_t* tr = t + (size_t)row * D_;
    float v[4]; float s = 0.f, s2 = 0.f;
    #pragma unroll
    for (int it = 0; it < 4; it++) {
        int j = tid + it * 256;
        v[it] = xr[j] + bf2f(tr[j]);
        s += v[it]; s2 += v[it] * v[it];
    }
    #pragma unroll
    for (int off = 32; off; off >>= 1) { s += __shfl_xor(s, off); s2 += __shfl_xor(s2, off); }
    __shared__ float rs[4], rq[4];
    if ((tid & 63) == 0) { rs[tid >> 6] = s; rq[tid >> 6] = s2; }
    __syncthreads();
    s = rs[0] + rs[1] + rs[2] + rs[3];
    s2 = rq[0] + rq[1] + rq[2] + rq[3];
    float mu = s * (1.f / D_);
    float var = s2 * (1.f / D_) - mu * mu;
    float rstd = rsqrtf(var + 1e-5f);
    #pragma unroll
    for (int it = 0; it < 4; it++) {
        int j = tid + it * 256;
        hb[(size_t)row * D_ + j] = f2bf((v[it] - mu) * rstd * g[j] + be[j]);
    }
}

__global__ __launch_bounds__(256) void ln2_kernel(const ushort_t* __restrict__ hbuf,
                                                  const ushort_t* __restrict__ t,
                                                  const float* __restrict__ g,
                                                  const float* __restrict__ be,
                                                  float* __restrict__ out) {
    int row = blockIdx.x, tid = threadIdx.x;
    const ushort_t* hr = hbuf + (size_t)row * D_;
    const ushort_t* tr = t + (size_t)row * D_;
    float v[4]; float s = 0.f, s2 = 0.f;
    #pragma unroll
    for (int it = 0; it < 4; it++) {
        int j = tid + it * 256;
        v[it] = bf2f(hr[j]) + bf2f(tr[j]);
        s += v[it]; s2 += v[it] * v[it];
    }
    #pragma unroll
    for (int off = 32; off; off >>= 1) { s += __shfl_xor(s, off); s2 += __shfl_xor(s2, off); }
    __shared__ float rs[4], rq[4];
    if ((tid & 63) == 0) { rs[tid >> 6] = s; rq[tid >> 6] = s2; }
    __syncthreads();
    s = rs[0] + rs[1] + rs[2] + rs[3];
    s2 = rq[0] + rq[1] + rq[2] + rq[3];
    float mu = s * (1.f / D_);
    float var = s2 * (1.f / D_) - mu * mu;
    float rstd = rsqrtf(var + 1e-5f);
    #pragma unroll
    for (int it = 0; it < 4; it++) {
        int j = tid + it * 256;
        out[(size_t)row * D_ + j] = (v[it] - mu) * rstd * g[j] + be[j];
    }
}

// ---------------------------------------------------------------- launch
extern "C" void kernel_launch(void* const* d_in, const int* in_sizes, int n_in,
                              void* d_out, int out_size, void* d_ws, size_t ws_size,
                              hipStream_t stream) {
    (void)in_sizes; (void)n_in; (void)out_size; (void)ws_size;
    const float* x   = (const float*)d_in[0];
    const int*   tok = (const int*)d_in[1];
    const float* pmi = (const float*)d_in[2];
    const float* Wq  = (const float*)d_in[3];
    const float* bq  = (const float*)d_in[4];
    const float* Wk  = (const float*)d_in[5];
    const float* bk  = (const float*)d_in[6];
    const float* Wv  = (const float*)d_in[7];
    const float* bv  = (const float*)d_in[8];
    const float* Wo  = (const float*)d_in[9];
    const float* bo  = (const float*)d_in[10];
    const float* W1  = (const float*)d_in[11];
    const float* b1  = (const float*)d_in[12];
    const float* W2  = (const float*)d_in[13];
    const float* b2  = (const float*)d_in[14];
    const float* g1  = (const float*)d_in[15];
    const float* be1 = (const float*)d_in[16];
    const float* g2  = (const float*)d_in[17];
    const float* be2 = (const float*)d_in[18];
    float* out = (float*)d_out;

    char* ws = (char*)d_ws;
    size_t off = 0;
    auto alloc = [&](size_t bytes) { char* p = ws + off; off += (bytes + 255) & ~(size_t)255; return p; };
    const size_t BSD = (size_t)B_ * S_ * D_;
    ushort_t* xb     = (ushort_t*)alloc(BSD * 2);                 // 16.8 MB
    ushort_t* WqkvT  = (ushort_t*)alloc((size_t)3 * D_ * D_ * 2); // 6 MB (q,k,v contiguous)
    ushort_t* WoT    = (ushort_t*)alloc((size_t)D_ * D_ * 2);
    ushort_t* W1T    = (ushort_t*)alloc((size_t)D_ * F_ * 2);
    ushort_t* W2T    = (ushort_t*)alloc((size_t)F_ * D_ * 2);
    float*    bqkv   = (float*)alloc(3072 * 4);
    ushort_t* qkvb   = (ushort_t*)alloc(3 * BSD * 2);             // 50 MB (q,k,v)
    ushort_t* vT     = (ushort_t*)alloc(BSD * 2);
    ushort_t* biasb  = (ushort_t*)alloc((size_t)B_ * S_ * S_ * 2);
    ushort_t* extra  = (ushort_t*)alloc(BSD * 2);
    (void)extra;
    // aliases (strict stream-order reuse)
    ushort_t* qb    = qkvb;
    ushort_t* kb    = qkvb + BSD;
    ushort_t* vb    = qkvb + 2 * BSD;
    ushort_t* attnb = xb;           // xb dead after QKV GEMM
    ushort_t* tbuf  = qb;           // q dead after attention
    ushort_t* hb    = kb;           // k dead after attention
    ushort_t* ffb   = vb;           // v+vT+biasb+extra (64MB contiguous) dead after attention

    const size_t attn_lds = 2304 + 16 * 1028 * 4;              // 68096 B

    cast_x_kernel<<<8192, 256, 0, stream>>>(x, xb);
    transpose_cast_kernel<<<dim3(32, 32), dim3(32, 8), 0, stream>>>(Wq, WqkvT, D_, D_);
    transpose_cast_kernel<<<dim3(32, 32), dim3(32, 8), 0, stream>>>(Wk, WqkvT + (size_t)D_ * D_, D_, D_);
    transpose_cast_kernel<<<dim3(32, 32), dim3(32, 8), 0, stream>>>(Wv, WqkvT + (size_t)2 * D_ * D_, D_, D_);
    transpose_cast_kernel<<<dim3(32, 32), dim3(32, 8), 0, stream>>>(Wo, WoT, D_, D_);
    transpose_cast_kernel<<<dim3(128, 32), dim3(32, 8), 0, stream>>>(W1, W1T, D_, F_);
    transpose_cast_kernel<<<dim3(32, 128), dim3(32, 8), 0, stream>>>(W2, W2T, F_, D_);
    pack_bias3_kernel<<<12, 256, 0, stream>>>(bq, bk, bv, bqkv);
    bias_gather_kernel<<<B_ * S_, 256, 0, stream>>>(tok, pmi, biasb);

    gemm_bt<<<dim3(24, 64), 256, 0, stream>>>(xb, WqkvT, bqkv, qkvb, B_ * S_, 3 * D_, D_, 2);
    transpose_v_kernel<<<B_ * H_ * (S_ / 64), 256, 0, stream>>>(vb, vT);

    attn_kernel<<<B_ * H_ * (S_ / 16), 256, attn_lds, stream>>>(qb, kb, vT, biasb, attnb);

    gemm_bt<<<dim3(8, 64), 256, 0, stream>>>(attnb, WoT, bo, tbuf, B_ * S_, D_, D_, 0);
    ln1_kernel<<<B_ * S_, 256, 0, stream>>>(x, tbuf, g1, be1, hb);
    gemm_bt<<<dim3(32, 64), 256, 0, stream>>>(hb, W1T, b1, ffb, B_ * S_, F_, D_, 1);
    gemm_bt<<<dim3(8, 64), 256, 0, stream>>>(ffb, W2T, b2, tbuf, B_ * S_, D_, F_, 0);
    ln2_kernel<<<B_ * S_, 256, 0, stream>>>(hb, tbuf, g2, be2, out);
}

// Round 3
// 1179.259 us; speedup vs baseline: 1.5275x; 1.2089x over previous
//
#include <hip/hip_runtime.h>
#include <cstdint>
#include <cstddef>

// Problem constants
#define B_   8
#define S_   1024
#define D_   1024
#define H_   16
#define HD_  64
#define F_   4096
#define V_   8192
#define KTOP 64

typedef unsigned short ushort_t;
typedef __attribute__((ext_vector_type(8))) short short8;            // MFMA bf16 A/B frag (4 VGPR)
typedef __attribute__((ext_vector_type(8))) _Float16 half8;          // MFMA f16 A/B frag
typedef __attribute__((ext_vector_type(4))) float floatx4;           // MFMA C/D frag
typedef __attribute__((ext_vector_type(4))) unsigned int uintx4;     // 16B copy
typedef __attribute__((ext_vector_type(4))) float floatv4;
typedef __attribute__((ext_vector_type(4))) unsigned short ushortx4;
typedef __attribute__((ext_vector_type(8))) unsigned short ushortx8;

__device__ __forceinline__ ushort_t f2bf(float f) {
    unsigned int u = __builtin_bit_cast(unsigned int, f);
    u += 0x7fffu + ((u >> 16) & 1u);            // round-to-nearest-even
    return (ushort_t)(u >> 16);
}
__device__ __forceinline__ float bf2f(ushort_t u) {
    unsigned int x = ((unsigned int)u) << 16;
    return __builtin_bit_cast(float, x);
}
__device__ __forceinline__ ushort_t f2h(float f) {
    _Float16 h = (_Float16)f;
    return __builtin_bit_cast(ushort_t, h);
}
__device__ __forceinline__ float h2f(ushort_t u) {
    return (float)__builtin_bit_cast(_Float16, u);
}

// async global->LDS, 16B per lane; lds dest = wave-uniform base + lane*16
__device__ __forceinline__ void gload_lds16(const ushort_t* g, ushort_t* lds_base) {
    __builtin_amdgcn_global_load_lds(
        (const __attribute__((address_space(1))) unsigned int*)g,
        (__attribute__((address_space(3))) unsigned int*)lds_base,
        16, 0, 0);
}

// ---------------------------------------------------------------- cast x -> bf16
__global__ __launch_bounds__(256) void cast_x_kernel(const float* __restrict__ x,
                                                     ushort_t* __restrict__ xb) {
    int gid = blockIdx.x * 256 + threadIdx.x;   // 4 elems per thread
    floatv4 v = ((const floatv4*)x)[gid];
    ushortx4 o;
    o[0] = f2bf(v[0]); o[1] = f2bf(v[1]); o[2] = f2bf(v[2]); o[3] = f2bf(v[3]);
    ((ushortx4*)xb)[gid] = o;
}

// ------------------------------------------- transpose + cast weight: W(K,N) -> WT(N,K) bf16, * scale
__global__ void transpose_cast_kernel(const float* __restrict__ W, ushort_t* __restrict__ WT,
                                      int K, int N, float scale) {
    __shared__ float tile[32][33];
    int n0 = blockIdx.x * 32, k0 = blockIdx.y * 32;
    #pragma unroll
    for (int i = threadIdx.y; i < 32; i += 8)
        tile[i][threadIdx.x] = W[(size_t)(k0 + i) * N + n0 + threadIdx.x];
    __syncthreads();
    #pragma unroll
    for (int i = threadIdx.y; i < 32; i += 8)
        WT[(size_t)(n0 + i) * K + k0 + threadIdx.x] = f2bf(tile[threadIdx.x][i] * scale);
}

// ---------------------------------------------------------------- pack q/k/v biases (bq scaled 1/8)
__global__ __launch_bounds__(256) void pack_bias3_kernel(const float* __restrict__ bq,
                                                         const float* __restrict__ bk,
                                                         const float* __restrict__ bv,
                                                         float* __restrict__ o) {
    int i = blockIdx.x * 256 + threadIdx.x;   // 3072 total
    float v = (i < 1024) ? bq[i] * 0.125f : (i < 2048) ? bk[i - 1024] : bv[i - 2048];
    o[i] = v;
}

// ---------------------------------------------------------------- pmi bias gather -> fp16 (ALPHA folded)
__global__ __launch_bounds__(256) void bias_gather_kernel(const int* __restrict__ tok,
                                                          const float* __restrict__ pmi,
                                                          ushort_t* __restrict__ biasb) {
    int b = blockIdx.x >> 10;
    int i = blockIdx.x & (S_ - 1);
    int ti = tok[b * S_ + i];
    const float* prow = pmi + (size_t)ti * V_;
    #pragma unroll
    for (int it = 0; it < 4; it++) {
        int j = threadIdx.x + it * 256;
        int tj = tok[b * S_ + j];
        biasb[(size_t)blockIdx.x * S_ + j] = f2h(0.1f * prow[tj]);
    }
}

// ---------------------------------------------------------------- V (B,H,S,HD) bf16 -> vT (B,H,HD,S) fp16
__global__ __launch_bounds__(256) void transpose_v_kernel(const ushort_t* __restrict__ v,
                                                          ushort_t* __restrict__ vT) {
    __shared__ ushort_t t[64 * 72];   // [s_loc][d], stride 72
    int bh = blockIdx.x >> 4;
    int s0 = (blockIdx.x & 15) * 64;
    #pragma unroll
    for (int it = 0; it < 2; it++) {
        int idx = threadIdx.x + it * 256;
        int sl = idx >> 3, dg = (idx & 7) * 8;
        *(uintx4*)&t[sl * 72 + dg] = *(const uintx4*)&v[((size_t)bh * S_ + s0 + sl) * HD_ + dg];
    }
    __syncthreads();
    #pragma unroll
    for (int it = 0; it < 2; it++) {
        int idx = threadIdx.x + it * 256;
        int dl = idx >> 3, sg = (idx & 7) * 8;
        ushortx8 o;
        #pragma unroll
        for (int i = 0; i < 8; i++) o[i] = f2h(bf2f(t[(sg + i) * 72 + dl]));
        *(ushortx8*)&vT[((size_t)bh * HD_ + dl) * S_ + s0 + sg] = o;
    }
}

// ---------------------------------------------------------------- GEMM: C = A(M,K) @ BT(N,K)^T + bias
// ep: 0 = bf16 row-major out ; 1 = + exact GELU ; 2 = fused QKV -> (3,B,H,S,HD)
__global__ __launch_bounds__(256) void gemm_bt(const ushort_t* __restrict__ A,
                                               const ushort_t* __restrict__ BT,
                                               const float* __restrict__ bias,
                                               ushort_t* __restrict__ C,
                                               int M, int N, int K, int ep) {
    __shared__ ushort_t As[128 * 32];   // unpadded: required by global_load_lds lane mapping
    __shared__ ushort_t Bs[128 * 32];

    const int tid = threadIdx.x;
    const int wid = tid >> 6, lane = tid & 63;
    const int quad = lane >> 4, r = lane & 15;
    const int wr = wid >> 1, wc = wid & 1;
    const int m0 = blockIdx.y * 128, n0 = blockIdx.x * 128;

    floatx4 acc[4][4];
    #pragma unroll
    for (int a = 0; a < 4; a++)
        #pragma unroll
        for (int b = 0; b < 4; b++) acc[a][b] = (floatx4){0.f, 0.f, 0.f, 0.f};

    // staging map: wave wid covers 16 rows/call; lane -> (row=lane>>2, col8=(lane&3)*8)
    const int srow = wid * 16 + (lane >> 2);
    const int scol = (lane & 3) * 8;
    const ushort_t* Ag0 = A + (size_t)(m0 + srow) * K + scol;
    const ushort_t* Ag1 = A + (size_t)(m0 + 64 + srow) * K + scol;
    const ushort_t* Bg0 = BT + (size_t)(n0 + srow) * K + scol;
    const ushort_t* Bg1 = BT + (size_t)(n0 + 64 + srow) * K + scol;
    ushort_t* Asd0 = As + (wid * 16) * 32;
    ushort_t* Asd1 = As + (64 + wid * 16) * 32;
    ushort_t* Bsd0 = Bs + (wid * 16) * 32;
    ushort_t* Bsd1 = Bs + (64 + wid * 16) * 32;

    for (int k0 = 0; k0 < K; k0 += 32) {
        __syncthreads();
        gload_lds16(Ag0 + k0, Asd0);
        gload_lds16(Ag1 + k0, Asd1);
        gload_lds16(Bg0 + k0, Bsd0);
        gload_lds16(Bg1 + k0, Bsd1);
        __syncthreads();

        short8 af[4], bf[4];
        #pragma unroll
        for (int t = 0; t < 4; t++)
            af[t] = *(const short8*)&As[(wr * 64 + t * 16 + r) * 32 + quad * 8];
        #pragma unroll
        for (int t = 0; t < 4; t++)
            bf[t] = *(const short8*)&Bs[(wc * 64 + t * 16 + r) * 32 + quad * 8];
        #pragma unroll
        for (int tm = 0; tm < 4; tm++)
            #pragma unroll
            for (int tn = 0; tn < 4; tn++)
                acc[tm][tn] = __builtin_amdgcn_mfma_f32_16x16x32_bf16(af[tm], bf[tn], acc[tm][tn], 0, 0, 0);
    }

    #pragma unroll
    for (int tm = 0; tm < 4; tm++) {
        #pragma unroll
        for (int tn = 0; tn < 4; tn++) {
            const int n = n0 + wc * 64 + tn * 16 + r;      // C col = lane&15 (m89-verified)
            const float bv = bias[n];
            #pragma unroll
            for (int i2 = 0; i2 < 4; i2++) {
                const int m = m0 + wr * 64 + tm * 16 + quad * 4 + i2;  // row = quad*4+reg
                float v = acc[tm][tn][i2] + bv;
                if (ep == 1) v = 0.5f * v * (1.0f + erff(v * 0.70710678118654752f));
                size_t idx;
                if (ep == 2) {
                    // (b,s) x (tensor,h,d) -> tensor*(B,H,S,HD)
                    int tensor = n >> 10, nn = n & 1023;
                    idx = (size_t)tensor * (B_ * S_ * D_)
                        + (((size_t)(m >> 10) * H_ + (nn >> 6)) * S_ + (m & (S_ - 1))) * HD_ + (nn & (HD_ - 1));
                } else {
                    idx = (size_t)m * N + n;
                }
                C[idx] = f2bf(v);
            }
        }
    }
}

// ---------------------------------------------------------------- fused attention (per b,h,16-query tile)
// LDS: q tile 16x72 bf16 (2304B) + scores 16x1032 fp16 (33024B) = 35328B -> 4 blocks/CU
__global__ __launch_bounds__(256) void attn_kernel(const ushort_t* __restrict__ q,
                                                   const ushort_t* __restrict__ k,
                                                   const ushort_t* __restrict__ vT,
                                                   const ushort_t* __restrict__ biasb,
                                                   ushort_t* __restrict__ attnb) {
    extern __shared__ char smem[];
    ushort_t* q_lds = (ushort_t*)smem;                 // 16 x 72 bf16
    ushort_t* Sm = (ushort_t*)(smem + 2304);           // 16 x 1032 fp16 (stride 2064B, 16B aligned)
    _Float16* Smh = (_Float16*)Sm;
    const int SST = 1032;

    const int bid = blockIdx.x;
    const int b = bid >> 10;
    const int h = (bid >> 6) & (H_ - 1);
    const int i0 = (bid & 63) * 16;
    const int tid = threadIdx.x;
    const int wid = tid >> 6, lane = tid & 63;
    const int quad = lane >> 4, r = lane & 15;

    const size_t bh = (size_t)b * H_ + h;
    const ushort_t* qbase = q + bh * S_ * HD_;
    const ushort_t* kbase = k + bh * S_ * HD_;
    const ushort_t* vbase = vT + bh * HD_ * S_;
    const ushort_t* bsrc = biasb + ((size_t)b * S_ + i0) * S_;  // 16 rows, contiguous 32KB

    // stage q tile (threads 0..127, bf16)
    if (tid < 128) {
        int row = tid >> 3, dg = (tid & 7) * 8;
        *(uintx4*)&q_lds[row * 72 + dg] = *(const uintx4*)&qbase[(size_t)(i0 + row) * HD_ + dg];
    }
    // stage bias fp16 via async global->LDS: 32 chunks of 1KB (zero VALU, conflict-free)
    #pragma unroll
    for (int c8 = 0; c8 < 8; c8++) {
        int c = wid * 8 + c8;
        int row = c >> 1, half = c & 1;
        gload_lds16(bsrc + (size_t)row * S_ + half * 512 + lane * 8,
                    Sm + row * SST + half * 512);
    }
    __syncthreads();

    // ---- QK^T: score = q*K^T + bias (0.125 scale pre-folded into Wq/bq); acc init from bias
    short8 aq0 = *(const short8*)&q_lds[r * 72 + quad * 8];        // A[m=lane&15][k=quad*8+j]
    short8 aq1 = *(const short8*)&q_lds[r * 72 + 32 + quad * 8];
    #pragma unroll 4
    for (int t = 0; t < 16; t++) {
        int jt = (t * 4 + wid) * 16;
        floatx4 acc;
        #pragma unroll
        for (int i2 = 0; i2 < 4; i2++)
            acc[i2] = (float)Smh[(quad * 4 + i2) * SST + jt + r];
        const ushort_t* kp = kbase + (size_t)(jt + r) * HD_ + quad * 8;  // B[k][n=lane&15] = K[n][k]
        short8 b0 = *(const short8*)kp;
        short8 b1 = *(const short8*)(kp + 32);
        acc = __builtin_amdgcn_mfma_f32_16x16x32_bf16(aq0, b0, acc, 0, 0, 0);
        acc = __builtin_amdgcn_mfma_f32_16x16x32_bf16(aq1, b1, acc, 0, 0, 0);
        #pragma unroll
        for (int i2 = 0; i2 < 4; i2++)
            Smh[(quad * 4 + i2) * SST + jt + r] = (_Float16)acc[i2];
    }
    __syncthreads();

    // ---- exact top-64 on fp16 scores: 16-bit radix select, ballot-counted (scalar-pipe adds).
    for (int rr = 0; rr < 4; rr++) {
        int row = wid * 4 + rr;
        const ushort_t* Srow = Sm + row * SST;
        float sv[16]; unsigned int kk[16];
        float mx = -3.4e38f;
        #pragma unroll
        for (int t = 0; t < 16; t++) {
            unsigned int u = Srow[t * 64 + lane];
            sv[t] = h2f((ushort_t)u);
            kk[t] = (u & 0x8000u) ? (0xFFFFu & ~u) : (u | 0x8000u);   // order-map, 16-bit key
            mx = fmaxf(mx, sv[t]);
        }
        #pragma unroll
        for (int off = 32; off; off >>= 1) mx = fmaxf(mx, __shfl_xor(mx, off));
        unsigned int T = 0u;                 // largest T with count(key>=T) >= 64
        for (int bit = 15; bit >= 0; bit--) {
            unsigned int trial = T | (1u << bit);
            int c = 0;
            #pragma unroll
            for (int t = 0; t < 16; t++)
                c += __popcll(__ballot(kk[t] >= trial));
            if (c >= KTOP) T = trial;
        }
        float ev[16]; float sum = 0.f;
        #pragma unroll
        for (int t = 0; t < 16; t++) {
            ev[t] = (kk[t] >= T) ? __expf(sv[t] - mx) : 0.f;   // ties kept (matches >= kth)
            sum += ev[t];
        }
        #pragma unroll
        for (int off = 32; off; off >>= 1) sum += __shfl_xor(sum, off);
        float inv = 1.f / sum;
        ushort_t* wrow = (ushort_t*)Srow;
        #pragma unroll
        for (int t = 0; t < 16; t++) wrow[t * 64 + lane] = f2h(ev[t] * inv);
    }
    __syncthreads();

    // ---- PV (f16 MFMA): attn(16 x 64) = W(16 x 1024) @ V(1024 x 64); wave wid owns d-tile wid*16
    floatx4 oacc = (floatx4){0.f, 0.f, 0.f, 0.f};
    for (int ks = 0; ks < 32; ks++) {
        half8 wa = *(const half8*)&Smh[r * SST + ks * 32 + quad * 8];
        half8 vbf = *(const half8*)&vbase[(size_t)(wid * 16 + r) * S_ + ks * 32 + quad * 8];
        oacc = __builtin_amdgcn_mfma_f32_16x16x32_f16(wa, vbf, oacc, 0, 0, 0);
    }
    #pragma unroll
    for (int i2 = 0; i2 < 4; i2++) {
        int row = quad * 4 + i2;
        attnb[((size_t)b * S_ + i0 + row) * D_ + h * HD_ + wid * 16 + r] = f2bf(oacc[i2]);
    }
}

// ---------------------------------------------------------------- layernorm kernels
__global__ __launch_bounds__(256) void ln1_kernel(const float* __restrict__ x,
                                                  const ushort_t* __restrict__ t,
                                                  const float* __restrict__ g,
                                                  const float* __restrict__ be,
                                                  ushort_t* __restrict__ hb) {
    int row = blockIdx.x, tid = threadIdx.x;
    const float* xr = x + (size_t)row * D_;
    const ushort_t* tr = t + (size_t)row * D_;
    float v[4]; float s = 0.f, s2 = 0.f;
    #pragma unroll
    for (int it = 0; it < 4; it++) {
        int j = tid + it * 256;
        v[it] = xr[j] + bf2f(tr[j]);
        s += v[it]; s2 += v[it] * v[it];
    }
    #pragma unroll
    for (int off = 32; off; off >>= 1) { s += __shfl_xor(s, off); s2 += __shfl_xor(s2, off); }
    __shared__ float rs[4], rq[4];
    if ((tid & 63) == 0) { rs[tid >> 6] = s; rq[tid >> 6] = s2; }
    __syncthreads();
    s = rs[0] + rs[1] + rs[2] + rs[3];
    s2 = rq[0] + rq[1] + rq[2] + rq[3];
    float mu = s * (1.f / D_);
    float var = s2 * (1.f / D_) - mu * mu;
    float rstd = rsqrtf(var + 1e-5f);
    #pragma unroll
    for (int it = 0; it < 4; it++) {
        int j = tid + it * 256;
        hb[(size_t)row * D_ + j] = f2bf((v[it] - mu) * rstd * g[j] + be[j]);
    }
}

__global__ __launch_bounds__(256) void ln2_kernel(const ushort_t* __restrict__ hbuf,
                                                  const ushort_t* __restrict__ t,
                                                  const float* __restrict__ g,
                                                  const float* __restrict__ be,
                                                  float* __restrict__ out) {
    int row = blockIdx.x, tid = threadIdx.x;
    const ushort_t* hr = hbuf + (size_t)row * D_;
    const ushort_t* tr = t + (size_t)row * D_;
    float v[4]; float s = 0.f, s2 = 0.f;
    #pragma unroll
    for (int it = 0; it < 4; it++) {
        int j = tid + it * 256;
        v[it] = bf2f(hr[j]) + bf2f(tr[j]);
        s += v[it]; s2 += v[it] * v[it];
    }
    #pragma unroll
    for (int off = 32; off; off >>= 1) { s += __shfl_xor(s, off); s2 += __shfl_xor(s2, off); }
    __shared__ float rs[4], rq[4];
    if ((tid & 63) == 0) { rs[tid >> 6] = s; rq[tid >> 6] = s2; }
    __syncthreads();
    s = rs[0] + rs[1] + rs[2] + rs[3];
    s2 = rq[0] + rq[1] + rq[2] + rq[3];
    float mu = s * (1.f / D_);
    float var = s2 * (1.f / D_) - mu * mu;
    float rstd = rsqrtf(var + 1e-5f);
    #pragma unroll
    for (int it = 0; it < 4; it++) {
        int j = tid + it * 256;
        out[(size_t)row * D_ + j] = (v[it] - mu) * rstd * g[j] + be[j];
    }
}

// ---------------------------------------------------------------- launch
extern "C" void kernel_launch(void* const* d_in, const int* in_sizes, int n_in,
                              void* d_out, int out_size, void* d_ws, size_t ws_size,
                              hipStream_t stream) {
    (void)in_sizes; (void)n_in; (void)out_size; (void)ws_size;
    const float* x   = (const float*)d_in[0];
    const int*   tok = (const int*)d_in[1];
    const float* pmi = (const float*)d_in[2];
    const float* Wq  = (const float*)d_in[3];
    const float* bq  = (const float*)d_in[4];
    const float* Wk  = (const float*)d_in[5];
    const float* bk  = (const float*)d_in[6];
    const float* Wv  = (const float*)d_in[7];
    const float* bv  = (const float*)d_in[8];
    const float* Wo  = (const float*)d_in[9];
    const float* bo  = (const float*)d_in[10];
    const float* W1  = (const float*)d_in[11];
    const float* b1  = (const float*)d_in[12];
    const float* W2  = (const float*)d_in[13];
    const float* b2  = (const float*)d_in[14];
    const float* g1  = (const float*)d_in[15];
    const float* be1 = (const float*)d_in[16];
    const float* g2  = (const float*)d_in[17];
    const float* be2 = (const float*)d_in[18];
    float* out = (float*)d_out;

    char* ws = (char*)d_ws;
    size_t off = 0;
    auto alloc = [&](size_t bytes) { char* p = ws + off; off += (bytes + 255) & ~(size_t)255; return p; };
    const size_t BSD = (size_t)B_ * S_ * D_;
    ushort_t* xb     = (ushort_t*)alloc(BSD * 2);                 // 16.8 MB
    ushort_t* WqkvT  = (ushort_t*)alloc((size_t)3 * D_ * D_ * 2); // 6 MB (q,k,v contiguous)
    ushort_t* WoT    = (ushort_t*)alloc((size_t)D_ * D_ * 2);
    ushort_t* W1T    = (ushort_t*)alloc((size_t)D_ * F_ * 2);
    ushort_t* W2T    = (ushort_t*)alloc((size_t)F_ * D_ * 2);
    float*    bqkv   = (float*)alloc(3072 * 4);
    ushort_t* qkvb   = (ushort_t*)alloc(3 * BSD * 2);             // 50 MB (q,k,v)
    ushort_t* vT     = (ushort_t*)alloc(BSD * 2);
    ushort_t* biasb  = (ushort_t*)alloc((size_t)B_ * S_ * S_ * 2);
    ushort_t* extra  = (ushort_t*)alloc(BSD * 2);
    (void)extra;
    // aliases (strict stream-order reuse)
    ushort_t* qb    = qkvb;
    ushort_t* kb    = qkvb + BSD;
    ushort_t* vb    = qkvb + 2 * BSD;
    ushort_t* attnb = xb;           // xb dead after QKV GEMM
    ushort_t* tbuf  = qb;           // q dead after attention
    ushort_t* hb    = kb;           // k dead after attention
    ushort_t* ffb   = vb;           // v+vT+biasb+extra (64MB contiguous) dead after attention

    const size_t attn_lds = 2304 + 16 * 1032 * 2;              // 35328 B -> 4 blocks/CU

    cast_x_kernel<<<8192, 256, 0, stream>>>(x, xb);
    transpose_cast_kernel<<<dim3(32, 32), dim3(32, 8), 0, stream>>>(Wq, WqkvT, D_, D_, 0.125f);
    transpose_cast_kernel<<<dim3(32, 32), dim3(32, 8), 0, stream>>>(Wk, WqkvT + (size_t)D_ * D_, D_, D_, 1.0f);
    transpose_cast_kernel<<<dim3(32, 32), dim3(32, 8), 0, stream>>>(Wv, WqkvT + (size_t)2 * D_ * D_, D_, D_, 1.0f);
    transpose_cast_kernel<<<dim3(32, 32), dim3(32, 8), 0, stream>>>(Wo, WoT, D_, D_, 1.0f);
    transpose_cast_kernel<<<dim3(128, 32), dim3(32, 8), 0, stream>>>(W1, W1T, D_, F_, 1.0f);
    transpose_cast_kernel<<<dim3(32, 128), dim3(32, 8), 0, stream>>>(W2, W2T, F_, D_, 1.0f);
    pack_bias3_kernel<<<12, 256, 0, stream>>>(bq, bk, bv, bqkv);
    bias_gather_kernel<<<B_ * S_, 256, 0, stream>>>(tok, pmi, biasb);

    gemm_bt<<<dim3(24, 64), 256, 0, stream>>>(xb, WqkvT, bqkv, qkvb, B_ * S_, 3 * D_, D_, 2);
    transpose_v_kernel<<<B_ * H_ * (S_ / 64), 256, 0, stream>>>(vb, vT);

    attn_kernel<<<B_ * H_ * (S_ / 16), 256, attn_lds, stream>>>(qb, kb, vT, biasb, attnb);

    gemm_bt<<<dim3(8, 64), 256, 0, stream>>>(attnb, WoT, bo, tbuf, B_ * S_, D_, D_, 0);
    ln1_kernel<<<B_ * S_, 256, 0, stream>>>(x, tbuf, g1, be1, hb);
    gemm_bt<<<dim3(32, 64), 256, 0, stream>>>(hb, W1T, b1, ffb, B_ * S_, F_, D_, 1);
    gemm_bt<<<dim3(8, 64), 256, 0, stream>>>(ffb, W2T, b2, tbuf, B_ * S_, D_, F_, 0);
    ln2_kernel<<<B_ * S_, 256, 0, stream>>>(hb, tbuf, g2, be2, out);
}